// Round 2
// baseline (95.306 us; speedup 1.0000x reference)
//
#include <hip/hip_runtime.h>

#define NBINS 64
#define HB (2 * NBINS)          // 128 bins total (sim + dis)
#define HIST_BLOCKS 1024
#define SEGS 8                  // final-kernel reduction segments

__device__ __forceinline__ void accum_point(float x, float* h) {
    // clip to [-1,1]; u = (x+1)/LAM with 1/LAM = (R-1)/2 = 31.5 exactly
    float s = fminf(fmaxf(x, -1.0f), 1.0f);
    float u = (s + 1.0f) * 31.5f;          // in [0, 63]
    int   b = (int)u;                      // floor (u >= 0)
    float f = u - (float)b;                // frac
    // exact bin-center (f==0) contributes 0 in the reference (strict ineqs);
    // guard also makes b+1 <= 63 whenever we add (b==63 only when f==0).
    if (f > 0.0f) {
        atomicAdd(&h[b],     1.0f - f);
        atomicAdd(&h[b + 1], f);
    }
}

__global__ __launch_bounds__(256) void hist_kernel(
        const float* __restrict__ sim,
        const float* __restrict__ dis,
        float* __restrict__ partials,  // [gridDim.x][HB]
        int n) {
    // per-wave sub-histograms: no inter-wave LDS atomic contention
    __shared__ float h[4 * HB];
    for (int i = threadIdx.x; i < 4 * HB; i += blockDim.x) h[i] = 0.0f;
    __syncthreads();

    float* hw = &h[(threadIdx.x >> 6) * HB];   // this wave's 128-bin copy

    int tid = blockIdx.x * blockDim.x + threadIdx.x;
    int nthreads = gridDim.x * blockDim.x;
    int nvec = n >> 2;
    const float4* sim4 = (const float4*)sim;
    const float4* dis4 = (const float4*)dis;

    for (int i = tid; i < nvec; i += nthreads) {
        float4 s4 = sim4[i];
        float4 d4 = dis4[i];
        accum_point(s4.x, hw);
        accum_point(s4.y, hw);
        accum_point(s4.z, hw);
        accum_point(s4.w, hw);
        accum_point(d4.x, hw + NBINS);
        accum_point(d4.y, hw + NBINS);
        accum_point(d4.z, hw + NBINS);
        accum_point(d4.w, hw + NBINS);
    }
    for (int i = (nvec << 2) + tid; i < n; i += nthreads) {
        accum_point(sim[i], hw);
        accum_point(dis[i], hw + NBINS);
    }

    __syncthreads();
    // fold 4 wave-copies -> 1, store per-block partial (coalesced, no atomics)
    if (threadIdx.x < HB) {
        int j = threadIdx.x;
        float v = h[j] + h[HB + j] + h[2 * HB + j] + h[3 * HB + j];
        partials[blockIdx.x * HB + j] = v;
    }
}

__global__ __launch_bounds__(1024) void final_kernel(
        const float* __restrict__ partials,  // [HIST_BLOCKS][HB]
        float* __restrict__ out, float invN) {
    __shared__ float red[SEGS * HB];
    __shared__ float tot[HB];

    // stage 1: 1024 threads = 8 segments x 128 bins; each sums 128 blocks
    int t = threadIdx.x;
    int j = t & (HB - 1);
    int seg = t >> 7;
    const int blocks_per_seg = HIST_BLOCKS / SEGS;   // 128
    float s = 0.0f;
    int base = seg * blocks_per_seg;
    #pragma unroll 4
    for (int k = 0; k < blocks_per_seg; ++k)
        s += partials[(base + k) * HB + j];          // lane-coalesced (consecutive j)
    red[seg * HB + j] = s;
    __syncthreads();

    // stage 2: fold 8 segments
    if (t < HB) {
        float v = 0.0f;
        #pragma unroll
        for (int g = 0; g < SEGS; ++g) v += red[g * HB + t];
        tot[t] = v;
    }
    __syncthreads();

    // stage 3: wave 0 does the 64-lane scan + dots
    if (t < 64) {
        int lane = t;
        float hp = tot[lane] * invN;
        float hm = tot[NBINS + lane] * invN;

        float hpc = hp, hmc = hm;
        #pragma unroll
        for (int off = 1; off < 64; off <<= 1) {
            float a = __shfl_up(hpc, off, 64);
            float b = __shfl_up(hmc, off, 64);
            if (lane >= off) { hpc += a; hmc += b; }
        }

        const float q = 0.9f, p = 0.1f;
        float v = q * q * hpc * hm
                - q * p * hpc * hp
                - q * p * hmc * hm
                + p * p * hmc * hp;

        #pragma unroll
        for (int off = 32; off >= 1; off >>= 1) v += __shfl_down(v, off, 64);

        if (lane == 0) out[0] = v / 0.64f;   // (1-2P)^2 = 0.64
    }
}

extern "C" void kernel_launch(void* const* d_in, const int* in_sizes, int n_in,
                              void* d_out, int out_size, void* d_ws, size_t ws_size,
                              hipStream_t stream) {
    const float* sim = (const float*)d_in[0];
    const float* dis = (const float*)d_in[1];
    int n = in_sizes[0];
    float* partials = (float*)d_ws;   // HIST_BLOCKS * HB floats = 512 KB, fully overwritten

    hist_kernel<<<HIST_BLOCKS, 256, 0, stream>>>(sim, dis, partials, n);
    final_kernel<<<1, 1024, 0, stream>>>(partials, (float*)d_out, 1.0f / (float)n);
}

// Round 3
// 89.933 us; speedup vs baseline: 1.0597x; 1.0597x over previous
//
#include <hip/hip_runtime.h>

#define NBINS 64
#define HB (2 * NBINS)          // 128 bins total (sim + dis)
#define HIST_BLOCKS 512
#define HIST_THREADS 512        // 8 waves/block
#define WAVES_PER_BLOCK (HIST_THREADS / 64)
#define SEGS 8                  // final-kernel reduction segments

__device__ __forceinline__ void accum_point(float x, float* h) {
    // clip to [-1,1]; u = (x+1)/LAM with 1/LAM = (R-1)/2 = 31.5 exactly
    float s = fminf(fmaxf(x, -1.0f), 1.0f);
    float u = (s + 1.0f) * 31.5f;          // in [0, 63]
    int   b = (int)u;                      // floor (u >= 0)
    float f = u - (float)b;                // frac
    // f==0 (exact bin center, incl. x=+-1) contributes 0 in the reference
    // (strict inequalities); guard also keeps b+1 <= 63.
    if (f > 0.0f) {
        atomicAdd(&h[b],     1.0f - f);
        atomicAdd(&h[b + 1], f);
    }
}

__global__ __launch_bounds__(HIST_THREADS) void hist_kernel(
        const float* __restrict__ sim,
        const float* __restrict__ dis,
        float* __restrict__ partials,  // [HIST_BLOCKS][HB]
        int n) {
    // per-wave sub-histograms: no inter-wave LDS atomic contention
    __shared__ float h[WAVES_PER_BLOCK * HB];
    for (int i = threadIdx.x; i < WAVES_PER_BLOCK * HB; i += blockDim.x)
        h[i] = 0.0f;
    __syncthreads();

    float* hw = &h[(threadIdx.x >> 6) * HB];   // this wave's 128-bin copy

    int tid = blockIdx.x * blockDim.x + threadIdx.x;
    int nthreads = gridDim.x * blockDim.x;     // 262144 == n/4 exactly
    int nvec = n >> 2;
    const float4* sim4 = (const float4*)sim;
    const float4* dis4 = (const float4*)dis;

    for (int i = tid; i < nvec; i += nthreads) {
        float4 s4 = sim4[i];
        float4 d4 = dis4[i];
        accum_point(s4.x, hw);
        accum_point(s4.y, hw);
        accum_point(s4.z, hw);
        accum_point(s4.w, hw);
        accum_point(d4.x, hw + NBINS);
        accum_point(d4.y, hw + NBINS);
        accum_point(d4.z, hw + NBINS);
        accum_point(d4.w, hw + NBINS);
    }
    for (int i = (nvec << 2) + tid; i < n; i += nthreads) {
        accum_point(sim[i], hw);
        accum_point(dis[i], hw + NBINS);
    }

    __syncthreads();
    // fold wave-copies -> 1, store per-block partial (coalesced, no atomics)
    if (threadIdx.x < HB) {
        int j = threadIdx.x;
        float v = 0.0f;
        #pragma unroll
        for (int w = 0; w < WAVES_PER_BLOCK; ++w) v += h[w * HB + j];
        partials[blockIdx.x * HB + j] = v;
    }
}

__global__ __launch_bounds__(1024) void final_kernel(
        const float* __restrict__ partials,  // [HIST_BLOCKS][HB]
        float* __restrict__ out, float invN) {
    __shared__ float red[SEGS * HB];
    __shared__ float tot[HB];

    // stage 1: 1024 threads = 8 segments x 128 bins; each sums 64 blocks
    int t = threadIdx.x;
    int j = t & (HB - 1);
    int seg = t >> 7;
    const int blocks_per_seg = HIST_BLOCKS / SEGS;   // 64
    float s = 0.0f;
    int base = seg * blocks_per_seg;
    #pragma unroll 4
    for (int k = 0; k < blocks_per_seg; ++k)
        s += partials[(base + k) * HB + j];          // lane-coalesced over j
    red[seg * HB + j] = s;
    __syncthreads();

    // stage 2: fold 8 segments
    if (t < HB) {
        float v = 0.0f;
        #pragma unroll
        for (int g = 0; g < SEGS; ++g) v += red[g * HB + t];
        tot[t] = v;
    }
    __syncthreads();

    // stage 3: wave 0 does the 64-lane scan + dots
    if (t < 64) {
        int lane = t;
        float hp = tot[lane] * invN;
        float hm = tot[NBINS + lane] * invN;

        float hpc = hp, hmc = hm;
        #pragma unroll
        for (int off = 1; off < 64; off <<= 1) {
            float a = __shfl_up(hpc, off, 64);
            float b = __shfl_up(hmc, off, 64);
            if (lane >= off) { hpc += a; hmc += b; }
        }

        const float q = 0.9f, p = 0.1f;
        float v = q * q * hpc * hm
                - q * p * hpc * hp
                - q * p * hmc * hm
                + p * p * hmc * hp;

        #pragma unroll
        for (int off = 32; off >= 1; off >>= 1) v += __shfl_down(v, off, 64);

        if (lane == 0) out[0] = v / 0.64f;   // (1-2P)^2 = 0.64
    }
}

extern "C" void kernel_launch(void* const* d_in, const int* in_sizes, int n_in,
                              void* d_out, int out_size, void* d_ws, size_t ws_size,
                              hipStream_t stream) {
    const float* sim = (const float*)d_in[0];
    const float* dis = (const float*)d_in[1];
    int n = in_sizes[0];
    float* partials = (float*)d_ws;   // HIST_BLOCKS * HB floats = 256 KB, fully overwritten

    hist_kernel<<<HIST_BLOCKS, HIST_THREADS, 0, stream>>>(sim, dis, partials, n);
    final_kernel<<<1, 1024, 0, stream>>>(partials, (float*)d_out, 1.0f / (float)n);
}